// Round 1
// 2924.050 us; speedup vs baseline: 1.6506x; 1.6506x over previous
//
#include <hip/hip_runtime.h>
#include <hip/hip_bf16.h>

// Problem constants
#define B_   128
#define T_   512
#define DIN  256
#define DH   1024
#define DOUT 1024

typedef short bf16x8 __attribute__((ext_vector_type(8)));
typedef float f32x4  __attribute__((ext_vector_type(4)));
typedef unsigned short u16;

static __device__ __forceinline__ u16 f2bf(float f) {
    unsigned u = __float_as_uint(f);
    u += 0x7FFFu + ((u >> 16) & 1u);
    return (u16)(u >> 16);
}
static __device__ __forceinline__ float bf2f(u16 h) {
    return __uint_as_float(((unsigned)h) << 16);
}

// Fragment layout per (t, group): element (r in 0..15, col in 0..1023) at
//   idx = (col>>5)*512 + ((col>>3)&3)*128 + r*8 + (col&7)   [u16 units]
// A-frag read for k-tile kt: lane l loads 16B at u16 offset kt*512 + l*8  (coalesced)

// ---------------- elementwise helpers ----------------

__global__ void f32_to_bf16_k(const float* __restrict__ in, u16* __restrict__ out, int n) {
    int i = blockIdx.x * 256 + threadIdx.x;
    int stride = gridDim.x * 256;
    for (; i < n; i += stride) out[i] = f2bf(in[i]);
}

__global__ void zero32_k(unsigned* __restrict__ p, int n) {
    int i = blockIdx.x * 256 + threadIdx.x;
    if (i < n) p[i] = 0;
}

__global__ void zero_row0_k(float* __restrict__ out) {
    int i = blockIdx.x * 256 + threadIdx.x;   // 128*1024 threads
    int b = i >> 10, c = i & 1023;
    out[(size_t)b * ((T_ + 1) * DOUT) + c] = 0.f;
}

// ---------------- phase 1: X = seq @ Wx^T + Wx_b + Wh_b -> frag layout ----------------

__global__ void proj_x_k(const u16* __restrict__ seqb, const u16* __restrict__ Wx,
                         const float* __restrict__ Wx_b, const float* __restrict__ Wh_b,
                         u16* __restrict__ Xf) {
    int wave = threadIdx.x >> 6;
    int lane = threadIdx.x & 63;
    int g = blockIdx.x * 4 + wave;           // 0..65535
    int mt = g >> 4, nt = g & 15;
    int t = mt >> 3, gb = mt & 7;
    int n0 = nt << 6;
    int lr = lane & 15, lq = lane >> 4;

    int b = gb * 16 + lr;
    const u16* Arow = seqb + (size_t)(b * T_ + t) * DIN;

    f32x4 acc[4] = {};
    for (int k0 = 0; k0 < DIN; k0 += 32) {
        bf16x8 a = *(const bf16x8*)(Arow + k0 + lq * 8);
#pragma unroll
        for (int f = 0; f < 4; ++f) {
            const u16* Brow = Wx + (size_t)(n0 + f * 16 + lr) * DIN;
            acc[f] = __builtin_amdgcn_mfma_f32_16x16x32_bf16(a, *(const bf16x8*)(Brow + k0 + lq * 8), acc[f], 0, 0, 0);
        }
    }
    u16* Xg = Xf + ((size_t)t * 8 + gb) * 16384;
#pragma unroll
    for (int f = 0; f < 4; ++f)
#pragma unroll
        for (int j = 0; j < 4; ++j) {
            int r = lq * 4 + j;
            int col = n0 + f * 16 + lr;
            float v = acc[f][j] + Wx_b[col] + Wh_b[col];
            Xg[(col >> 5) * 512 + ((col >> 3) & 3) * 128 + r * 8 + (col & 7)] = f2bf(v);
        }
}

// ---------------- phase 2: persistent recurrence ----------------
// 128 blocks x 256 threads, all co-resident. Block = (colblk 0..15, gb 0..7).
// 4 waves: colh = w&1 (32-col half), kh = w>>1 (512-K half).
// Wh slice (32 cols x 512 K) lives in registers for the whole kernel.
//
// Coherence scheme (NO agent acquire/release -> no per-step buffer_inv/wbl2):
//  - hbuf (cross-block): explicit sc0 sc1 loads/stores -> L1+L2 bypass, coherent
//    at the Infinity Cache regardless of block->XCD placement.
//  - cnt: RELAXED agent-scope atomics (RMW + spin load execute at the MALL).
//  - release ordering: asm s_waitcnt vmcnt(0) (store ack from coherence point)
//    before __syncthreads -> leader increments. Consumer loads issue in-order
//    after the spin-load resolves (wave issue is in-order).
//  - Xf / Wh are block-private / read-only: normal cached path, untouched by
//    any cache maintenance now.

__global__ __launch_bounds__(256, 1) void rnn_persist_k(
    const u16* __restrict__ Wh, u16* __restrict__ Xf,
    u16* __restrict__ hbuf, int* __restrict__ cnt)
{
    const int tid  = threadIdx.x;
    const int lane = tid & 63;
    const int w    = tid >> 6;
    const int colh = w & 1, kh = w >> 1;
    const int gb     = blockIdx.x & 7;
    const int colblk = blockIdx.x >> 3;      // 0..15
    const int n0c = colblk * 64 + colh * 32;
    const int lr = lane & 15, lq = lane >> 4;

    // preload Wh B-frags: 32 frags x 16B/lane = 128 VGPRs
    bf16x8 Bf0[16], Bf1[16];
    {
        const u16* wr = Wh + (size_t)(n0c + lr) * DH + kh * 512;
#pragma unroll
        for (int kt = 0; kt < 16; ++kt) {
            Bf0[kt] = *(const bf16x8*)(wr + kt * 32 + lq * 8);
            Bf1[kt] = *(const bf16x8*)(wr + 16 * DH + kt * 32 + lq * 8);
        }
    }

    __shared__ f32x4 xch[2][2][64];          // [colh][frag f][lane]

    // finalize column for this lane (frag f = kh): c fixed per lane
    const int c = n0c + kh * 16 + lr;
    const int fbase = (c >> 5) * 512 + ((c >> 3) & 3) * 128 + (c & 7);

    for (int t = 0; t < T_; ++t) {
        // prefetch this step's x-projection scalars (normal cached loads;
        // the vmcnt(0) inside the h-load asm below drains these too)
        u16* Xg = Xf + ((size_t)t * 8 + gb) * 16384;
        u16 xv[4];
#pragma unroll
        for (int j = 0; j < 4; ++j) xv[j] = Xg[fbase + lq * 32 + j * 8];

        // h loads: device-coherent (sc0 sc1 = bypass L1+L2, read from MALL).
        // Self-contained asm block: 16 x dwordx4 + one vmcnt(0).
        const u16* hin = hbuf + (size_t)(t & 1) * 131072 + gb * 16384 + kh * 8192;
        const u16* p0 = hin + lane * 8;      // byte stride 16 per lane
        const u16* p1 = p0 + 2048;           // +4096 B
        const u16* p2 = p0 + 4096;           // +8192 B
        const u16* p3 = p0 + 6144;           // +12288 B
        bf16x8 af[16];
        asm volatile(
            "global_load_dwordx4 %0, %16, off sc0 sc1\n\t"
            "global_load_dwordx4 %1, %16, off offset:1024 sc0 sc1\n\t"
            "global_load_dwordx4 %2, %16, off offset:2048 sc0 sc1\n\t"
            "global_load_dwordx4 %3, %16, off offset:3072 sc0 sc1\n\t"
            "global_load_dwordx4 %4, %17, off sc0 sc1\n\t"
            "global_load_dwordx4 %5, %17, off offset:1024 sc0 sc1\n\t"
            "global_load_dwordx4 %6, %17, off offset:2048 sc0 sc1\n\t"
            "global_load_dwordx4 %7, %17, off offset:3072 sc0 sc1\n\t"
            "global_load_dwordx4 %8, %18, off sc0 sc1\n\t"
            "global_load_dwordx4 %9, %18, off offset:1024 sc0 sc1\n\t"
            "global_load_dwordx4 %10, %18, off offset:2048 sc0 sc1\n\t"
            "global_load_dwordx4 %11, %18, off offset:3072 sc0 sc1\n\t"
            "global_load_dwordx4 %12, %19, off sc0 sc1\n\t"
            "global_load_dwordx4 %13, %19, off offset:1024 sc0 sc1\n\t"
            "global_load_dwordx4 %14, %19, off offset:2048 sc0 sc1\n\t"
            "global_load_dwordx4 %15, %19, off offset:3072 sc0 sc1\n\t"
            "s_waitcnt vmcnt(0)"
            : "=&v"(af[0]), "=&v"(af[1]), "=&v"(af[2]), "=&v"(af[3]),
              "=&v"(af[4]), "=&v"(af[5]), "=&v"(af[6]), "=&v"(af[7]),
              "=&v"(af[8]), "=&v"(af[9]), "=&v"(af[10]), "=&v"(af[11]),
              "=&v"(af[12]), "=&v"(af[13]), "=&v"(af[14]), "=&v"(af[15])
            : "v"(p0), "v"(p1), "v"(p2), "v"(p3)
            : "memory");

        // 4 independent 8-deep accumulate chains (was 2 x 16-deep)
        f32x4 a0a = {}, a0b = {}, a1a = {}, a1b = {};
#pragma unroll
        for (int kt = 0; kt < 16; kt += 2) {
            a0a = __builtin_amdgcn_mfma_f32_16x16x32_bf16(af[kt],     Bf0[kt],     a0a, 0, 0, 0);
            a1a = __builtin_amdgcn_mfma_f32_16x16x32_bf16(af[kt],     Bf1[kt],     a1a, 0, 0, 0);
            a0b = __builtin_amdgcn_mfma_f32_16x16x32_bf16(af[kt + 1], Bf0[kt + 1], a0b, 0, 0, 0);
            a1b = __builtin_amdgcn_mfma_f32_16x16x32_bf16(af[kt + 1], Bf1[kt + 1], a1b, 0, 0, 0);
        }
        f32x4 a0 = a0a + a0b;
        f32x4 a1 = a1a + a1b;

        // K-split combine: wave (colh,kh) finalizes frag f=kh, shares frag f=1-kh
        xch[colh][1 ^ kh][lane] = kh ? a0 : a1;
        __syncthreads();
        f32x4 mine = kh ? a1 : a0;
        f32x4 part = xch[colh][kh][lane];
        mine = mine + part;

        u16* hog = hbuf + (size_t)((t + 1) & 1) * 131072 + gb * 16384;
        unsigned hv[4];
#pragma unroll
        for (int j = 0; j < 4; ++j) {
            int idx = fbase + lq * 32 + j * 8;
            float s = mine[j] + bf2f(xv[j]);
            Xg[idx] = f2bf(s);               // S kept for phase 3 (normal cached store)
            hv[j] = f2bf(tanhf(s));
        }
        // h stores: device-coherent write-through (sc0 sc1)
        {
            const u16* hp = hog + fbase + lq * 32;
            asm volatile(
                "global_store_short %4, %0, off sc0 sc1\n\t"
                "global_store_short %4, %1, off offset:16 sc0 sc1\n\t"
                "global_store_short %4, %2, off offset:32 sc0 sc1\n\t"
                "global_store_short %4, %3, off offset:48 sc0 sc1"
                :: "v"(hv[0]), "v"(hv[1]), "v"(hv[2]), "v"(hv[3]), "v"(hp)
                : "memory");
        }

        if (t != T_ - 1) {
            // release: every thread drains its stores to the coherence point
            asm volatile("s_waitcnt vmcnt(0)" ::: "memory");
            __syncthreads();
            if (tid == 0) {
                int* c0 = &cnt[t * 8 + gb];
                __hip_atomic_fetch_add(c0, 1, __ATOMIC_RELAXED, __HIP_MEMORY_SCOPE_AGENT);
                while (__hip_atomic_load(c0, __ATOMIC_RELAXED, __HIP_MEMORY_SCOPE_AGENT) < 16)
                    __builtin_amdgcn_s_sleep(1);
            }
            __syncthreads();
        }
    }
}

// ---------------- phase 3: O = S @ Wo^T + Wo_b -> d_out[b, t+1, :] ----------------

__global__ void wo_k(const u16* __restrict__ XSf, const u16* __restrict__ Wo,
                     const float* __restrict__ Wo_b, float* __restrict__ out) {
    int wave = threadIdx.x >> 6;
    int lane = threadIdx.x & 63;
    int g = blockIdx.x * 4 + wave;           // 0..65535
    int mt = g >> 4, nt = g & 15;
    int n0 = nt << 6;
    int lr = lane & 15, lq = lane >> 4;

    const u16* Ab = XSf + (size_t)mt * 16384;

    f32x4 acc[4] = {};
    for (int kt = 0; kt < 32; ++kt) {
        bf16x8 a = *(const bf16x8*)(Ab + kt * 512 + lane * 8);
#pragma unroll
        for (int f = 0; f < 4; ++f) {
            const u16* Brow = Wo + (size_t)(n0 + f * 16 + lr) * DH;
            acc[f] = __builtin_amdgcn_mfma_f32_16x16x32_bf16(a, *(const bf16x8*)(Brow + kt * 32 + lq * 8), acc[f], 0, 0, 0);
        }
    }
    int t = mt >> 3, gb = mt & 7;
#pragma unroll
    for (int f = 0; f < 4; ++f)
#pragma unroll
        for (int j = 0; j < 4; ++j) {
            int b = gb * 16 + lq * 4 + j;
            int col = n0 + f * 16 + lr;
            out[(size_t)b * ((T_ + 1) * DOUT) + (size_t)(t + 1) * DOUT + col] = acc[f][j] + Wo_b[col];
        }
}

// ---------------- launcher ----------------

extern "C" void kernel_launch(void* const* d_in, const int* in_sizes, int n_in,
                              void* d_out, int out_size, void* d_ws, size_t ws_size,
                              hipStream_t stream) {
    const float* seq  = (const float*)d_in[0];
    const float* Wh_w = (const float*)d_in[1];
    const float* Wh_b = (const float*)d_in[2];
    const float* Wx_w = (const float*)d_in[3];
    const float* Wx_b = (const float*)d_in[4];
    const float* Wo_w = (const float*)d_in[5];
    const float* Wo_b = (const float*)d_in[6];
    float* out = (float*)d_out;

    size_t off = 0;
    auto carve = [&](size_t bytes) {
        void* p = (char*)d_ws + off;
        off += (bytes + 255) & ~(size_t)255;
        return p;
    };
    u16* seqb = (u16*)carve((size_t)B_ * T_ * DIN * 2);
    u16* Whb  = (u16*)carve((size_t)DH * DH * 2);
    u16* Wxb  = (u16*)carve((size_t)DH * DIN * 2);
    u16* Wob  = (u16*)carve((size_t)DH * DH * 2);
    u16* Xf   = (u16*)carve((size_t)T_ * B_ * DH * 2);   // X, overwritten by S in place (frag layout)
    u16* hbuf = (u16*)carve((size_t)2 * B_ * DH * 2);    // double-buffered h, frag layout
    int* cnt  = (int*)carve((size_t)T_ * 8 * 4);

    // phase 0: casts
    f32_to_bf16_k<<<2048, 256, 0, stream>>>(seq,  seqb, B_ * T_ * DIN);
    f32_to_bf16_k<<<256,  256, 0, stream>>>(Wh_w, Whb,  DH * DH);
    f32_to_bf16_k<<<64,   256, 0, stream>>>(Wx_w, Wxb,  DH * DIN);
    f32_to_bf16_k<<<256,  256, 0, stream>>>(Wo_w, Wob,  DH * DH);

    // phase 1: input projection (+ both biases folded in), frag layout
    proj_x_k<<<16384, 256, 0, stream>>>(seqb, Wxb, Wx_b, Wh_b, Xf);

    // zero h0 and barrier counters
    zero32_k<<<256, 256, 0, stream>>>((unsigned*)hbuf, B_ * DH / 2);
    zero32_k<<<16,  256, 0, stream>>>((unsigned*)cnt, T_ * 8);

    // phase 2: persistent recurrence (128 blocks, all co-resident)
    rnn_persist_k<<<128, 256, 0, stream>>>(Whb, Xf, hbuf, cnt);

    // phase 3: output projection
    zero_row0_k<<<(B_ * DOUT + 255) / 256, 256, 0, stream>>>(out);
    wo_k<<<16384, 256, 0, stream>>>(Xf, Wob, Wo_b, out);
}

// Round 3
// 2036.930 us; speedup vs baseline: 2.3694x; 1.4355x over previous
//
#include <hip/hip_runtime.h>
#include <hip/hip_bf16.h>

// Problem constants
#define B_   128
#define T_   512
#define DIN  256
#define DH   1024
#define DOUT 1024

typedef short bf16x8 __attribute__((ext_vector_type(8)));
typedef float f32x4  __attribute__((ext_vector_type(4)));
typedef unsigned short u16;

static __device__ __forceinline__ u16 f2bf(float f) {
    unsigned u = __float_as_uint(f);
    u += 0x7FFFu + ((u >> 16) & 1u);
    return (u16)(u >> 16);
}
static __device__ __forceinline__ float bf2f(u16 h) {
    return __uint_as_float(((unsigned)h) << 16);
}

// Fragment layout per (t, group): element (r in 0..15, col in 0..1023) at
//   idx = (col>>5)*512 + ((col>>3)&3)*128 + r*8 + (col&7)   [u16 units]
// A-frag read for k-tile kt: lane l loads 16B at u16 offset kt*512 + l*8  (coalesced)

// ---------------- elementwise helpers ----------------

__global__ void f32_to_bf16_k(const float* __restrict__ in, u16* __restrict__ out, int n4) {
    int i = blockIdx.x * 256 + threadIdx.x;
    int stride = gridDim.x * 256;
    for (; i < n4; i += stride) {
        float4 v = ((const float4*)in)[i];
        ushort4 o;
        o.x = f2bf(v.x); o.y = f2bf(v.y); o.z = f2bf(v.z); o.w = f2bf(v.w);
        ((ushort4*)out)[i] = o;
    }
}

__global__ void zero32_k(unsigned* __restrict__ p, int n) {
    int i = blockIdx.x * 256 + threadIdx.x;
    if (i < n) p[i] = 0;
}

__global__ void zero_row0_k(float* __restrict__ out) {
    int i = blockIdx.x * 256 + threadIdx.x;   // 128*1024 threads
    int b = i >> 10, c = i & 1023;
    out[(size_t)b * ((T_ + 1) * DOUT) + c] = 0.f;
}

// ---------------- phase 1: X = seq @ Wx^T + Wx_b + Wh_b -> frag layout ----------------
// 64 rows x 64 cols per wave (4 row-groups): 4x less Wx/seq re-read traffic.

__global__ void proj_x_k(const u16* __restrict__ seqb, const u16* __restrict__ Wx,
                         const float* __restrict__ Wx_b, const float* __restrict__ Wh_b,
                         u16* __restrict__ Xf) {
    int wave = threadIdx.x >> 6;
    int lane = threadIdx.x & 63;
    int g = blockIdx.x * 4 + wave;           // 0..16383
    int mt4 = g >> 4;                        // 0..1023 (4 row-groups each)
    int nt = g & 15;
    int n0 = nt << 6;
    int lr = lane & 15, lq = lane >> 4;

    const u16* Ar[4];
#pragma unroll
    for (int r = 0; r < 4; ++r) {
        int mt = mt4 * 4 + r;
        int t = mt >> 3, gbv = mt & 7;
        Ar[r] = seqb + (size_t)((gbv * 16 + lr) * T_ + t) * DIN;
    }
    const u16* B0 = Wx + (size_t)(n0 + lr) * DIN;

    f32x4 acc[4][4] = {};
    for (int k0 = 0; k0 < DIN; k0 += 32) {
        bf16x8 a[4], b[4];
#pragma unroll
        for (int r = 0; r < 4; ++r) a[r] = *(const bf16x8*)(Ar[r] + k0 + lq * 8);
#pragma unroll
        for (int f = 0; f < 4; ++f) b[f] = *(const bf16x8*)(B0 + (size_t)f * 16 * DIN + k0 + lq * 8);
#pragma unroll
        for (int r = 0; r < 4; ++r)
#pragma unroll
            for (int f = 0; f < 4; ++f)
                acc[r][f] = __builtin_amdgcn_mfma_f32_16x16x32_bf16(a[r], b[f], acc[r][f], 0, 0, 0);
    }
#pragma unroll
    for (int r = 0; r < 4; ++r) {
        int mt = mt4 * 4 + r;
        int t = mt >> 3, gbv = mt & 7;
        u16* Xg = Xf + ((size_t)t * 8 + gbv) * 16384;
#pragma unroll
        for (int f = 0; f < 4; ++f)
#pragma unroll
            for (int j = 0; j < 4; ++j) {
                int rr = lq * 4 + j;
                int col = n0 + f * 16 + lr;
                float v = acc[r][f][j] + Wx_b[col] + Wh_b[col];
                Xg[(col >> 5) * 512 + ((col >> 3) & 3) * 128 + rr * 8 + (col & 7)] = f2bf(v);
            }
    }
}

// ---------------- phase 2: persistent recurrence ----------------
// 128 blocks x 256 threads, all co-resident. Block = (colblk 0..15, gb 0..7).
// 4 waves: colh = w&1 (32-col half), kh = w>>1 (512-K half).
// Wh slice (32 cols x 512 K) lives in registers for the whole kernel.
//
// Coherence: hbuf via sc0 sc1 (coherent at MALL, placement-independent);
// cnt via relaxed agent atomics; release = vmcnt(0) store drain. No L2
// flush/inv anywhere. Xf/Wh stay on the normal cached path.
//
// Outputs (h, S) are staged in LDS and stored as coalesced dwordx4: each
// block's output is a contiguous 2KB region [colblk*1024, +1024) u16.

__global__ __launch_bounds__(256, 1) void rnn_persist_k(
    const u16* __restrict__ Wh, u16* __restrict__ Xf,
    u16* __restrict__ hbuf, int* __restrict__ cnt)
{
    const int tid  = threadIdx.x;
    const int lane = tid & 63;
    const int w    = tid >> 6;
    const int colh = w & 1, kh = w >> 1;
    const int gb     = blockIdx.x & 7;
    const int colblk = blockIdx.x >> 3;      // 0..15
    const int n0c = colblk * 64 + colh * 32;
    const int lr = lane & 15, lq = lane >> 4;

    // preload Wh B-frags: 32 frags x 16B/lane = 128 VGPRs
    bf16x8 Bf0[16], Bf1[16];
    {
        const u16* wr = Wh + (size_t)(n0c + lr) * DH + kh * 512;
#pragma unroll
        for (int kt = 0; kt < 16; ++kt) {
            Bf0[kt] = *(const bf16x8*)(wr + kt * 32 + lq * 8);
            Bf1[kt] = *(const bf16x8*)(wr + 16 * DH + kt * 32 + lq * 8);
        }
    }

    __shared__ f32x4 xch[2][2][64];          // K-split exchange, 4 KB
    __shared__ u16 sS[1024];                 // S staging, 2 KB
    __shared__ u16 sH[1024];                 // h staging, 2 KB

    // finalize column for this lane (frag f = kh): c fixed per lane
    const int c = n0c + kh * 16 + lr;
    const int fbase = (c >> 5) * 512 + ((c >> 3) & 3) * 128 + (c & 7);
    // local (in-block) offset of fbase: fbase - colblk*1024
    const int lfb = colh * 512 + (kh * 2 + (lr >> 3)) * 128 + (lr & 7);

    // prologue: prefetch x(0)
    u16 xv[4];
    {
        const u16* Xg0 = Xf + (size_t)gb * 16384;
#pragma unroll
        for (int j = 0; j < 4; ++j) xv[j] = Xg0[fbase + lq * 32 + j * 8];
    }

    for (int t = 0; t < T_; ++t) {
        // h loads: device-coherent (sc0 sc1). Self-contained asm block:
        // 16 x dwordx4 + one vmcnt(0) (also drains the xv prefetch).
        const u16* hin = hbuf + (size_t)(t & 1) * 131072 + gb * 16384 + kh * 8192;
        const u16* p0 = hin + lane * 8;      // byte stride 16 per lane
        const u16* p1 = p0 + 2048;           // +4096 B
        const u16* p2 = p0 + 4096;           // +8192 B
        const u16* p3 = p0 + 6144;           // +12288 B
        bf16x8 af[16];
        asm volatile(
            "global_load_dwordx4 %0, %16, off sc0 sc1\n\t"
            "global_load_dwordx4 %1, %16, off offset:1024 sc0 sc1\n\t"
            "global_load_dwordx4 %2, %16, off offset:2048 sc0 sc1\n\t"
            "global_load_dwordx4 %3, %16, off offset:3072 sc0 sc1\n\t"
            "global_load_dwordx4 %4, %17, off sc0 sc1\n\t"
            "global_load_dwordx4 %5, %17, off offset:1024 sc0 sc1\n\t"
            "global_load_dwordx4 %6, %17, off offset:2048 sc0 sc1\n\t"
            "global_load_dwordx4 %7, %17, off offset:3072 sc0 sc1\n\t"
            "global_load_dwordx4 %8, %18, off sc0 sc1\n\t"
            "global_load_dwordx4 %9, %18, off offset:1024 sc0 sc1\n\t"
            "global_load_dwordx4 %10, %18, off offset:2048 sc0 sc1\n\t"
            "global_load_dwordx4 %11, %18, off offset:3072 sc0 sc1\n\t"
            "global_load_dwordx4 %12, %19, off sc0 sc1\n\t"
            "global_load_dwordx4 %13, %19, off offset:1024 sc0 sc1\n\t"
            "global_load_dwordx4 %14, %19, off offset:2048 sc0 sc1\n\t"
            "global_load_dwordx4 %15, %19, off offset:3072 sc0 sc1\n\t"
            "s_waitcnt vmcnt(0)"
            : "=&v"(af[0]), "=&v"(af[1]), "=&v"(af[2]), "=&v"(af[3]),
              "=&v"(af[4]), "=&v"(af[5]), "=&v"(af[6]), "=&v"(af[7]),
              "=&v"(af[8]), "=&v"(af[9]), "=&v"(af[10]), "=&v"(af[11]),
              "=&v"(af[12]), "=&v"(af[13]), "=&v"(af[14]), "=&v"(af[15])
            : "v"(p0), "v"(p1), "v"(p2), "v"(p3)
            : "memory");

        // 4 independent 8-deep accumulate chains
        f32x4 a0a = {}, a0b = {}, a1a = {}, a1b = {};
#pragma unroll
        for (int kt = 0; kt < 16; kt += 2) {
            a0a = __builtin_amdgcn_mfma_f32_16x16x32_bf16(af[kt],     Bf0[kt],     a0a, 0, 0, 0);
            a1a = __builtin_amdgcn_mfma_f32_16x16x32_bf16(af[kt],     Bf1[kt],     a1a, 0, 0, 0);
            a0b = __builtin_amdgcn_mfma_f32_16x16x32_bf16(af[kt + 1], Bf0[kt + 1], a0b, 0, 0, 0);
            a1b = __builtin_amdgcn_mfma_f32_16x16x32_bf16(af[kt + 1], Bf1[kt + 1], a1b, 0, 0, 0);
        }
        f32x4 a0 = a0a + a0b;
        f32x4 a1 = a1a + a1b;

        // K-split combine: wave (colh,kh) finalizes frag f=kh, shares frag f=1-kh
        xch[colh][1 ^ kh][lane] = kh ? a0 : a1;
        __syncthreads();
        f32x4 mine = (kh ? a1 : a0) + xch[colh][kh][lane];

        // finalize: S = mine + x; h = tanh(S) via exp (err ~1e-6 << bf16 ulp)
#pragma unroll
        for (int j = 0; j < 4; ++j) {
            int li = lfb + (lq * 4 + j) * 8;
            float s = mine[j] + bf2f(xv[j]);
            sS[li] = f2bf(s);
            float e = __expf(2.f * s);
            sH[li] = f2bf(1.f - 2.f * __builtin_amdgcn_rcpf(e + 1.f));
        }
        __syncthreads();

        // coalesced 16B stores: waves 0-1 -> S (cached), waves 2-3 -> h (sc0 sc1)
        u16* XgR  = Xf + ((size_t)t * 8 + gb) * 16384 + colblk * 1024;
        u16* hogR = hbuf + (size_t)((t + 1) & 1) * 131072 + gb * 16384 + colblk * 1024;
        if (tid < 128) {
            *(bf16x8*)(XgR + tid * 8) = *(const bf16x8*)(sS + tid * 8);
        } else {
            int q = tid - 128;
            bf16x8 v = *(const bf16x8*)(sH + q * 8);
            const u16* hp = hogR + q * 8;
            asm volatile("global_store_dwordx4 %0, %1, off sc0 sc1"
                         :: "v"(hp), "v"(v) : "memory");
        }

        if (t != T_ - 1) {
            // prefetch x(t+1): in flight during store-drain + barrier
            const u16* Xgn = Xf + ((size_t)(t + 1) * 8 + gb) * 16384;
#pragma unroll
            for (int j = 0; j < 4; ++j) xv[j] = Xgn[fbase + lq * 32 + j * 8];

            // release: drain stores to the coherence point
            asm volatile("s_waitcnt vmcnt(0)" ::: "memory");
            __syncthreads();
            if (tid == 0) {
                int* c0 = &cnt[t * 8 + gb];
                __hip_atomic_fetch_add(c0, 1, __ATOMIC_RELAXED, __HIP_MEMORY_SCOPE_AGENT);
                while (__hip_atomic_load(c0, __ATOMIC_RELAXED, __HIP_MEMORY_SCOPE_AGENT) < 16)
                    __builtin_amdgcn_s_sleep(1);
            }
            __syncthreads();
        }
    }
}

// ---------------- phase 3: O = S @ Wo^T + Wo_b -> d_out[b, t+1, :] ----------------
// 64 rows x 64 cols per wave: 4x less Wo/S re-read traffic vs 16-row waves.

__global__ void wo_k(const u16* __restrict__ XSf, const u16* __restrict__ Wo,
                     const float* __restrict__ Wo_b, float* __restrict__ out) {
    int wave = threadIdx.x >> 6;
    int lane = threadIdx.x & 63;
    int g = blockIdx.x * 4 + wave;           // 0..16383
    int mt4 = g >> 4;                        // 0..1023
    int nt = g & 15;
    int n0 = nt << 6;
    int lr = lane & 15, lq = lane >> 4;

    const u16* Ab = XSf + (size_t)mt4 * 4 * 16384;
    const u16* B0 = Wo + (size_t)(n0 + lr) * DH;

    f32x4 acc[4][4] = {};
    for (int kt = 0; kt < 32; ++kt) {
        bf16x8 a[4], b[4];
#pragma unroll
        for (int r = 0; r < 4; ++r)
            a[r] = *(const bf16x8*)(Ab + (size_t)r * 16384 + kt * 512 + lane * 8);
#pragma unroll
        for (int f = 0; f < 4; ++f)
            b[f] = *(const bf16x8*)(B0 + (size_t)f * 16 * DH + kt * 32 + lq * 8);
#pragma unroll
        for (int r = 0; r < 4; ++r)
#pragma unroll
            for (int f = 0; f < 4; ++f)
                acc[r][f] = __builtin_amdgcn_mfma_f32_16x16x32_bf16(a[r], b[f], acc[r][f], 0, 0, 0);
    }
#pragma unroll
    for (int r = 0; r < 4; ++r) {
        int mt = mt4 * 4 + r;
        int t = mt >> 3, gbv = mt & 7;
#pragma unroll
        for (int f = 0; f < 4; ++f)
#pragma unroll
            for (int j = 0; j < 4; ++j) {
                int bb = gbv * 16 + lq * 4 + j;
                int col = n0 + f * 16 + lr;
                out[(size_t)bb * ((T_ + 1) * DOUT) + (size_t)(t + 1) * DOUT + col] = acc[r][f][j] + Wo_b[col];
            }
    }
}

// ---------------- launcher ----------------

extern "C" void kernel_launch(void* const* d_in, const int* in_sizes, int n_in,
                              void* d_out, int out_size, void* d_ws, size_t ws_size,
                              hipStream_t stream) {
    const float* seq  = (const float*)d_in[0];
    const float* Wh_w = (const float*)d_in[1];
    const float* Wh_b = (const float*)d_in[2];
    const float* Wx_w = (const float*)d_in[3];
    const float* Wx_b = (const float*)d_in[4];
    const float* Wo_w = (const float*)d_in[5];
    const float* Wo_b = (const float*)d_in[6];
    float* out = (float*)d_out;

    size_t off = 0;
    auto carve = [&](size_t bytes) {
        void* p = (char*)d_ws + off;
        off += (bytes + 255) & ~(size_t)255;
        return p;
    };
    u16* seqb = (u16*)carve((size_t)B_ * T_ * DIN * 2);
    u16* Whb  = (u16*)carve((size_t)DH * DH * 2);
    u16* Wxb  = (u16*)carve((size_t)DH * DIN * 2);
    u16* Wob  = (u16*)carve((size_t)DH * DH * 2);
    u16* Xf   = (u16*)carve((size_t)T_ * B_ * DH * 2);   // X, overwritten by S in place (frag layout)
    u16* hbuf = (u16*)carve((size_t)2 * B_ * DH * 2);    // double-buffered h, frag layout
    int* cnt  = (int*)carve((size_t)T_ * 8 * 4);

    // phase 0: casts (vectorized: float4 in, ushort4 out)
    f32_to_bf16_k<<<2048, 256, 0, stream>>>(seq,  seqb, B_ * T_ * DIN / 4);
    f32_to_bf16_k<<<64,   256, 0, stream>>>(Wh_w, Whb,  DH * DH / 4);
    f32_to_bf16_k<<<16,   256, 0, stream>>>(Wx_w, Wxb,  DH * DIN / 4);
    f32_to_bf16_k<<<64,   256, 0, stream>>>(Wo_w, Wob,  DH * DH / 4);

    // phase 1: input projection (+ both biases folded in), frag layout
    proj_x_k<<<4096, 256, 0, stream>>>(seqb, Wxb, Wx_b, Wh_b, Xf);

    // zero h0 and barrier counters
    zero32_k<<<256, 256, 0, stream>>>((unsigned*)hbuf, B_ * DH / 2);
    zero32_k<<<16,  256, 0, stream>>>((unsigned*)cnt, T_ * 8);

    // phase 2: persistent recurrence (128 blocks, all co-resident)
    rnn_persist_k<<<128, 256, 0, stream>>>(Whb, Xf, hbuf, cnt);

    // phase 3: output projection
    zero_row0_k<<<(B_ * DOUT + 255) / 256, 256, 0, stream>>>(out);
    wo_k<<<4096, 256, 0, stream>>>(Xf, Wob, Wo_b, out);
}